// Round 11
// baseline (55.330 us; speedup 1.0000x reference)
//
#include <hip/hip_runtime.h>
#include <hip/hip_bf16.h>

// SpatialAttention2D MFMA v10: B=2, C=64, N=4096, 4 heads x d=16, fp32 io.
// vs v9: attention is now REGISTER-DIRECT flash attention: no LDS tiles, no
// main-loop barriers, no staging. Fragments are loaded straight from the
// L2-resident workspace with per-lane permuted addresses (K frag = coalesced
// 512B/wave; V frag = 16x32B segments). Each wave: 32 q (2 Q-frags, so every
// K/V fragment feeds 2 QK + 2 PV MFMAs) x one key-quarter (1024 keys).
// Grid 1024 blocks x 4 waves = 4096 waves = 4/SIMD. Depth-1 register
// prefetch; epilogue-only barrier for the quarter combine.
// qkv_proj: byte-identical to r9's (best-total run) for clean attribution.

#define NTOK 4096
#define HD   16
#define BH   8
#define QUART 1024             // keys per wave (key-quarter)
#define PITERS (QUART/32)      // 32 pair-iters (2 chunks of 16 keys each)

typedef __attribute__((ext_vector_type(4))) short short4v;
typedef __attribute__((ext_vector_type(4))) float float4v;
typedef __attribute__((ext_vector_type(4))) ushort ushort4v;
typedef __attribute__((ext_vector_type(2))) unsigned uint2v;

__device__ __forceinline__ ushort f2bf(float f) {
  unsigned u = __builtin_bit_cast(unsigned, f);
  u += 0x7fffu + ((u >> 16) & 1u);          // round-to-nearest-even
  return (ushort)(u >> 16);
}

__device__ __forceinline__ float fast_exp2(float x) {
#if __has_builtin(__builtin_amdgcn_exp2f)
  return __builtin_amdgcn_exp2f(x);
#else
  return exp2f(x);
#endif
}

// packed f32x4 -> bf16x4 (RNE) via v_cvt_pk_bf16_f32 (v6b-verified form)
__device__ __forceinline__ short4v pack4_bf16(float a, float b, float c, float d) {
  __hip_bfloat162 lo = __float22bfloat162_rn(make_float2(a, b));
  __hip_bfloat162 hi = __float22bfloat162_rn(make_float2(c, d));
  unsigned ulo, uhi;
  __builtin_memcpy(&ulo, &lo, 4);
  __builtin_memcpy(&uhi, &hi, 4);
  uint2v u = { ulo, uhi };
  return __builtin_bit_cast(short4v, u);
}

// ws layout in ushort elements (3 MB total)
// Qt: [bh][d][n] (transposed), Kb: [bh][n][d], Vt: [bh][d][n]
#define QB_OFF 0
#define KB_OFF ((size_t)BH*NTOK*HD)
#define VT_OFF (2*(size_t)BH*NTOK*HD)

// ---------------------------------------------------------------------------
// Kernel 1: QKV projection (byte-identical to r9). 512 blocks x 192 threads,
// 2 tiles x 8 tokens. Weights in regs. Q scaled by 0.25*log2(e), stored
// [d][n]; V stored [d][n]; K stored [n][d].
// ---------------------------------------------------------------------------
__global__ __launch_bounds__(192) void qkv_proj(
    const float* __restrict__ x, const float* __restrict__ w,
    const float* __restrict__ bias, ushort* __restrict__ wsu) {
  const int TOK = 8, TILES = 2;
  int blk = blockIdx.x;            // 2 * 4096/16 = 512
  int b   = blk >> 8;
  int n00 = (blk & 255) * (TOK*TILES);
  int o   = threadIdx.x;           // 0..191

  float wr[64];
  const float4* w4 = reinterpret_cast<const float4*>(w + o*64);
  #pragma unroll
  for (int i = 0; i < 16; ++i) {
    float4 tt = w4[i];
    wr[4*i+0]=tt.x; wr[4*i+1]=tt.y; wr[4*i+2]=tt.z; wr[4*i+3]=tt.w;
  }
  float bb = bias[o];

  int part = o >> 6;               // 0=q,1=k,2=v
  int oo   = o & 63;
  int h    = oo >> 4;
  int dd   = oo & 15;
  int bh   = b*4 + h;
  const float QSCALE = 0.25f * 1.44269504f;

  ushort* Qt = wsu + QB_OFF;
  ushort* Kb = wsu + KB_OFF;
  ushort* Vt = wsu + VT_OFF;

  __shared__ float4 xs4[64][2];
  const float4* x4 = reinterpret_cast<const float4*>(x);

  #pragma unroll 1
  for (int tile = 0; tile < TILES; ++tile) {
    int n0 = n00 + tile*TOK;
    for (int idx = threadIdx.x; idx < 128; idx += 192) {
      int c = idx >> 1, t4 = idx & 1;
      xs4[c][t4] = x4[((size_t)b*64 + c)*(NTOK/4) + (n0 >> 2) + t4];
    }
    __syncthreads();

    #pragma unroll
    for (int t4 = 0; t4 < 2; ++t4) {
      float a[4] = {bb, bb, bb, bb};
      #pragma unroll
      for (int c = 0; c < 64; ++c) {
        float4 xv = xs4[c][t4];
        float wv = wr[c];
        a[0] = fmaf(xv.x, wv, a[0]);
        a[1] = fmaf(xv.y, wv, a[1]);
        a[2] = fmaf(xv.z, wv, a[2]);
        a[3] = fmaf(xv.w, wv, a[3]);
      }
      if (part == 0) {
        ushort4v vv = { f2bf(a[0]*QSCALE), f2bf(a[1]*QSCALE),
                        f2bf(a[2]*QSCALE), f2bf(a[3]*QSCALE) };
        *(ushort4v*)(Qt + ((size_t)bh*HD + dd)*NTOK + n0 + t4*4) = vv;
      } else if (part == 1) {
        #pragma unroll
        for (int j = 0; j < 4; ++j)
          Kb[((size_t)bh*NTOK + n0 + t4*4 + j)*HD + dd] = f2bf(a[j]);
      } else {
        ushort4v vv = { f2bf(a[0]), f2bf(a[1]), f2bf(a[2]), f2bf(a[3]) };
        *(ushort4v*)(Vt + ((size_t)bh*HD + dd)*NTOK + n0 + t4*4) = vv;
      }
    }
    __syncthreads();
  }
}

// ---------------------------------------------------------------------------
// Kernel 2: register-direct MFMA flash attention.
// Grid = 8 bh x 128 qblk(32q) = 1024 blocks x 256 threads (4 waves).
// Wave = key-quarter `quart`; all 4 waves cover the SAME 32 q.
// Per pair-iter (32 keys): 4 frag loads (global->reg), 4 QK MFMA, 16 exp2,
// 4 cvt-pack, 4 PV MFMA. No LDS in the main loop; combine in epilogue.
// ---------------------------------------------------------------------------
__global__ __launch_bounds__(256, 4) void attn_mfma(
    const ushort* __restrict__ wsu, float* __restrict__ out) {
  const ushort* Qt = wsu + QB_OFF;
  const ushort* Kb = wsu + KB_OFF;
  const ushort* Vt = wsu + VT_OFF;

  int bh    = blockIdx.x >> 7;
  int qblk  = blockIdx.x & 127;
  int tid   = threadIdx.x;
  int quart = tid >> 6;            // 0..3: key-quarter
  int lane  = tid & 63;
  int lr    = lane & 15;
  int g4    = (lane >> 4) << 2;
  int qbase = qblk*32;

  __shared__ float comb[3][64][11];   // 8.4 KB epilogue combine

  const ushort* Qh = Qt + (size_t)bh*HD*NTOK;                       // [d][n]
  const ushort* Kh = Kb + ((size_t)bh*NTOK + (size_t)quart*QUART)*HD;
  const ushort* Vh = Vt + (size_t)bh*HD*NTOK + quart*QUART;

  // Q fragments (B operand): lane l holds Q[q][d=g4..g4+3], q-groups 0/1
  short4v qf0, qf1;
  #pragma unroll
  for (int j = 0; j < 4; ++j) {
    qf0[j] = (short)Qh[(size_t)(g4+j)*NTOK + qbase      + lr];
    qf1[j] = (short)Qh[(size_t)(g4+j)*NTOK + qbase + 16 + lr];
  }

  // per-lane fragment pointers (ushort units):
  // K frag chunk c: lane l -> K[c*16 + lr][g4..g4+3] = Kh + c*256 + lr*16 + (l>>4)*4
  // V frag chunk c: lane l -> V^T[lr][c*16 + g4..g4+3] = Vh + lr*NTOK + c*16 + (l>>4)*4
  const ushort* kp = Kh + lr*HD + (lane >> 4)*4;      // + it*512 (+256 odd chunk)
  const ushort* vp = Vh + (size_t)lr*NTOK + (lane >> 4)*4;  // + it*32 (+16 odd)

  float4v a0e = {0.f,0.f,0.f,0.f}, a0o = {0.f,0.f,0.f,0.f};
  float4v a1e = {0.f,0.f,0.f,0.f}, a1o = {0.f,0.f,0.f,0.f};
  float l0 = 0.f, l1 = 0.f;

  // prologue: fragments for iter 0
  short4v kfe = *(const short4v*)(kp);
  short4v kfo = *(const short4v*)(kp + 256);
  short4v vfe = *(const short4v*)(vp);
  short4v vfo = *(const short4v*)(vp + 16);

  #pragma unroll 2
  for (int it = 0; it < PITERS; ++it) {
    // depth-1 register prefetch of next iter's fragments
    short4v nkfe, nkfo, nvfe, nvfo;
    if (it + 1 < PITERS) {
      nkfe = *(const short4v*)(kp + (it+1)*512);
      nkfo = *(const short4v*)(kp + (it+1)*512 + 256);
      nvfe = *(const short4v*)(vp + (it+1)*32);
      nvfo = *(const short4v*)(vp + (it+1)*32 + 16);
    }
    float4v zero = {0.f,0.f,0.f,0.f};
    __builtin_amdgcn_s_setprio(1);
    float4v s0e = __builtin_amdgcn_mfma_f32_16x16x16bf16_1k(kfe, qf0, zero, 0,0,0);
    float4v s0o = __builtin_amdgcn_mfma_f32_16x16x16bf16_1k(kfo, qf0, zero, 0,0,0);
    float4v s1e = __builtin_amdgcn_mfma_f32_16x16x16bf16_1k(kfe, qf1, zero, 0,0,0);
    float4v s1o = __builtin_amdgcn_mfma_f32_16x16x16bf16_1k(kfo, qf1, zero, 0,0,0);

    float p0e0 = fast_exp2(s0e[0]), p0e1 = fast_exp2(s0e[1]);
    float p0e2 = fast_exp2(s0e[2]), p0e3 = fast_exp2(s0e[3]);
    float p0o0 = fast_exp2(s0o[0]), p0o1 = fast_exp2(s0o[1]);
    float p0o2 = fast_exp2(s0o[2]), p0o3 = fast_exp2(s0o[3]);
    float p1e0 = fast_exp2(s1e[0]), p1e1 = fast_exp2(s1e[1]);
    float p1e2 = fast_exp2(s1e[2]), p1e3 = fast_exp2(s1e[3]);
    float p1o0 = fast_exp2(s1o[0]), p1o1 = fast_exp2(s1o[1]);
    float p1o2 = fast_exp2(s1o[2]), p1o3 = fast_exp2(s1o[3]);

    l0 += (p0e0 + p0e1) + (p0e2 + p0e3) + (p0o0 + p0o1) + (p0o2 + p0o3);
    l1 += (p1e0 + p1e1) + (p1e2 + p1e3) + (p1o0 + p1o1) + (p1o2 + p1o3);

    short4v pb0e = pack4_bf16(p0e0, p0e1, p0e2, p0e3);
    short4v pb0o = pack4_bf16(p0o0, p0o1, p0o2, p0o3);
    short4v pb1e = pack4_bf16(p1e0, p1e1, p1e2, p1e3);
    short4v pb1o = pack4_bf16(p1o0, p1o1, p1o2, p1o3);

    a0e = __builtin_amdgcn_mfma_f32_16x16x16bf16_1k(vfe, pb0e, a0e, 0,0,0);
    a0o = __builtin_amdgcn_mfma_f32_16x16x16bf16_1k(vfo, pb0o, a0o, 0,0,0);
    a1e = __builtin_amdgcn_mfma_f32_16x16x16bf16_1k(vfe, pb1e, a1e, 0,0,0);
    a1o = __builtin_amdgcn_mfma_f32_16x16x16bf16_1k(vfo, pb1o, a1o, 0,0,0);
    __builtin_amdgcn_s_setprio(0);

    kfe = nkfe; kfo = nkfo; vfe = nvfe; vfo = nvfo;
  }

  // per-wave partial outputs (key-quarter partials)
  float o0[4], o1[4];
  #pragma unroll
  for (int r = 0; r < 4; ++r) {
    o0[r] = a0e[r] + a0o[r];
    o1[r] = a1e[r] + a1o[r];
  }

  // combine the 4 quarters: waves 1..3 publish, wave 0 reduces + stores
  if (quart != 0) {
    float* cp = &comb[quart-1][lane][0];
    cp[0] = o0[0]; cp[1] = o0[1]; cp[2] = o0[2]; cp[3] = o0[3];
    cp[4] = o1[0]; cp[5] = o1[1]; cp[6] = o1[2]; cp[7] = o1[3];
    cp[8] = l0;    cp[9] = l1;
  }
  __syncthreads();
  if (quart == 0) {
    #pragma unroll
    for (int wv = 0; wv < 3; ++wv) {
      const float* cp = &comb[wv][lane][0];
      o0[0] += cp[0]; o0[1] += cp[1]; o0[2] += cp[2]; o0[3] += cp[3];
      o1[0] += cp[4]; o1[1] += cp[5]; o1[2] += cp[6]; o1[3] += cp[7];
      l0 += cp[8];    l1 += cp[9];
    }
    // total l per q (lanes l^16, l^32 hold the same q)
    l0 += __shfl_xor(l0, 16); l0 += __shfl_xor(l0, 32);
    l1 += __shfl_xor(l1, 16); l1 += __shfl_xor(l1, 32);
    float inv0 = 1.0f / l0, inv1 = 1.0f / l1;

    int b = bh >> 2, h = bh & 3;
    float* ob = out + ((size_t)(b*64 + h*16 + g4)) * NTOK;
    #pragma unroll
    for (int r = 0; r < 4; ++r) {
      ob[(size_t)r*NTOK + qbase      + lr] = o0[r] * inv0;
      ob[(size_t)r*NTOK + qbase + 16 + lr] = o1[r] * inv1;
    }
  }
}

extern "C" void kernel_launch(void* const* d_in, const int* in_sizes, int n_in,
                              void* d_out, int out_size, void* d_ws, size_t ws_size,
                              hipStream_t stream) {
  const float* x    = (const float*)d_in[0];   // (2,64,64,64)
  const float* w    = (const float*)d_in[1];   // (192,64)
  const float* bias = (const float*)d_in[2];   // (192,)
  float* out  = (float*)d_out;                 // (2,64,64,64)
  ushort* wsu = (ushort*)d_ws;                 // 3 MB used

  qkv_proj <<<512,  192, 0, stream>>>(x, w, bias, wsu);
  attn_mfma<<<1024, 256, 0, stream>>>(wsu, out);
}

// Round 12
// 41.348 us; speedup vs baseline: 1.3382x; 1.3382x over previous
//
#include <hip/hip_runtime.h>
#include <hip/hip_bf16.h>

// SpatialAttention2D MFMA v11: B=2, C=64, N=4096, 4 heads x d=16, fp32 io.
// vs v10 (reg-direct, latency-bound, scattered V): 
//  (1) V stored FRAGMENT-ORDERED in global ws (Vf[bh][chunk][lane*4]) so the
//      PV A-fragment load is a coalesced 512B/wave read, same form as K;
//  (2) depth-2 software pipeline with named A/B fragment sets (iters 2k,2k+1
//      computed while 2k+2,2k+3 are in flight), #pragma unroll 4;
//  (3) qkv byte-identical to r9 except the V store index (fragment-ordered).
// No LDS in the attn main loop; epilogue-only barrier (quarter combine).

#define NTOK 4096
#define HD   16
#define BH   8
#define QUART 1024             // keys per wave (key-quarter)
#define PIT2 (QUART/32/2)      // hmm: pair-iters = 32; loop runs PITERS/2 = 16
#define PITERS (QUART/32)      // 32 pair-iters (2 chunks of 16 keys each)

typedef __attribute__((ext_vector_type(4))) short short4v;
typedef __attribute__((ext_vector_type(4))) float float4v;
typedef __attribute__((ext_vector_type(4))) ushort ushort4v;
typedef __attribute__((ext_vector_type(2))) unsigned uint2v;

__device__ __forceinline__ ushort f2bf(float f) {
  unsigned u = __builtin_bit_cast(unsigned, f);
  u += 0x7fffu + ((u >> 16) & 1u);          // round-to-nearest-even
  return (ushort)(u >> 16);
}

__device__ __forceinline__ float fast_exp2(float x) {
#if __has_builtin(__builtin_amdgcn_exp2f)
  return __builtin_amdgcn_exp2f(x);
#else
  return exp2f(x);
#endif
}

// packed f32x4 -> bf16x4 (RNE) via v_cvt_pk_bf16_f32 (v6b-verified form)
__device__ __forceinline__ short4v pack4_bf16(float a, float b, float c, float d) {
  __hip_bfloat162 lo = __float22bfloat162_rn(make_float2(a, b));
  __hip_bfloat162 hi = __float22bfloat162_rn(make_float2(c, d));
  unsigned ulo, uhi;
  __builtin_memcpy(&ulo, &lo, 4);
  __builtin_memcpy(&uhi, &hi, 4);
  uint2v u = { ulo, uhi };
  return __builtin_bit_cast(short4v, u);
}

// ws layout in ushort elements (3 MB total)
// Qt: [bh][d][n] (transposed), Kb: [bh][n][d], Vf: [bh] fragment-ordered:
//   element (d, key) at bh*65536 + (key>>4)*256 + ((key&15)>>2)*64 + d*4 + (key&3)
#define QB_OFF 0
#define KB_OFF ((size_t)BH*NTOK*HD)
#define VT_OFF (2*(size_t)BH*NTOK*HD)

// ---------------------------------------------------------------------------
// Kernel 1: QKV projection (r9 structure; only the V store index differs).
// 512 blocks x 192 threads, 2 tiles x 8 tokens. Weights in regs.
// Q scaled by 0.25*log2(e), stored [d][n]; K stored [n][d]; V frag-ordered.
// ---------------------------------------------------------------------------
__global__ __launch_bounds__(192) void qkv_proj(
    const float* __restrict__ x, const float* __restrict__ w,
    const float* __restrict__ bias, ushort* __restrict__ wsu) {
  const int TOK = 8, TILES = 2;
  int blk = blockIdx.x;            // 512
  int b   = blk >> 8;
  int n00 = (blk & 255) * (TOK*TILES);
  int o   = threadIdx.x;           // 0..191

  float wr[64];
  const float4* w4 = reinterpret_cast<const float4*>(w + o*64);
  #pragma unroll
  for (int i = 0; i < 16; ++i) {
    float4 tt = w4[i];
    wr[4*i+0]=tt.x; wr[4*i+1]=tt.y; wr[4*i+2]=tt.z; wr[4*i+3]=tt.w;
  }
  float bb = bias[o];

  int part = o >> 6;               // 0=q,1=k,2=v
  int oo   = o & 63;
  int h    = oo >> 4;
  int dd   = oo & 15;
  int bh   = b*4 + h;
  const float QSCALE = 0.25f * 1.44269504f;

  ushort* Qt = wsu + QB_OFF;
  ushort* Kb = wsu + KB_OFF;
  ushort* Vf = wsu + VT_OFF;

  __shared__ float4 xs4[64][2];
  const float4* x4 = reinterpret_cast<const float4*>(x);

  #pragma unroll 1
  for (int tile = 0; tile < TILES; ++tile) {
    int n0 = n00 + tile*TOK;
    for (int idx = threadIdx.x; idx < 128; idx += 192) {
      int c = idx >> 1, t4 = idx & 1;
      xs4[c][t4] = x4[((size_t)b*64 + c)*(NTOK/4) + (n0 >> 2) + t4];
    }
    __syncthreads();

    #pragma unroll
    for (int t4 = 0; t4 < 2; ++t4) {
      float a[4] = {bb, bb, bb, bb};
      #pragma unroll
      for (int c = 0; c < 64; ++c) {
        float4 xv = xs4[c][t4];
        float wv = wr[c];
        a[0] = fmaf(xv.x, wv, a[0]);
        a[1] = fmaf(xv.y, wv, a[1]);
        a[2] = fmaf(xv.z, wv, a[2]);
        a[3] = fmaf(xv.w, wv, a[3]);
      }
      if (part == 0) {
        ushort4v vv = { f2bf(a[0]*QSCALE), f2bf(a[1]*QSCALE),
                        f2bf(a[2]*QSCALE), f2bf(a[3]*QSCALE) };
        *(ushort4v*)(Qt + ((size_t)bh*HD + dd)*NTOK + n0 + t4*4) = vv;
      } else if (part == 1) {
        #pragma unroll
        for (int j = 0; j < 4; ++j)
          Kb[((size_t)bh*NTOK + n0 + t4*4 + j)*HD + dd] = f2bf(a[j]);
      } else {
        // fragment-ordered V: 4 consecutive tokens (m..m+3, m%4==0) land at
        // consecutive ushorts: (m>>4)*256 + ((m&15)>>2)*64 + dd*4
        int m = n0 + t4*4;
        size_t idx = (size_t)bh*NTOK*HD + (m >> 4)*256 + ((m & 15) >> 2)*64 + dd*4;
        ushort4v vv = { f2bf(a[0]), f2bf(a[1]), f2bf(a[2]), f2bf(a[3]) };
        *(ushort4v*)(Vf + idx) = vv;
      }
    }
    __syncthreads();
  }
}

// ---------------------------------------------------------------------------
// Kernel 2: register-direct MFMA flash attention, depth-2 pipeline.
// Grid = 8 bh x 128 qblk(32q) = 1024 blocks x 256 threads (4 waves).
// Wave = key-quarter; all 4 waves cover the SAME 32 q. All frag loads are
// coalesced 512B/wave. Epilogue combines quarters via small LDS.
// ---------------------------------------------------------------------------
__global__ __launch_bounds__(256, 4) void attn_mfma(
    const ushort* __restrict__ wsu, float* __restrict__ out) {
  const ushort* Qt = wsu + QB_OFF;
  const ushort* Kb = wsu + KB_OFF;
  const ushort* Vt = wsu + VT_OFF;

  int bh    = blockIdx.x >> 7;
  int qblk  = blockIdx.x & 127;
  int tid   = threadIdx.x;
  int quart = tid >> 6;            // 0..3: key-quarter
  int lane  = tid & 63;
  int lr    = lane & 15;
  int g4    = (lane >> 4) << 2;
  int qbase = qblk*32;

  __shared__ float comb[3][64][11];   // 8.4 KB epilogue combine

  const ushort* Qh = Qt + (size_t)bh*HD*NTOK;                       // [d][n]
  const ushort* Kh = Kb + ((size_t)bh*NTOK + (size_t)quart*QUART)*HD;
  const ushort* Vh = Vt + (size_t)bh*NTOK*HD + (size_t)quart*QUART*HD;

  // Q fragments (B operand): lane l holds Q[q][d=g4..g4+3], q-groups 0/1
  short4v qf0, qf1;
  #pragma unroll
  for (int j = 0; j < 4; ++j) {
    qf0[j] = (short)Qh[(size_t)(g4+j)*NTOK + qbase      + lr];
    qf1[j] = (short)Qh[(size_t)(g4+j)*NTOK + qbase + 16 + lr];
  }

  // per-lane fragment pointers (ushort units); iter i reads at i*512 (+256)
  const ushort* kp = Kh + lr*HD + (lane >> 4)*4;
  const ushort* vp = Vh + lane*4;

  float4v a0e = {0.f,0.f,0.f,0.f}, a0o = {0.f,0.f,0.f,0.f};
  float4v a1e = {0.f,0.f,0.f,0.f}, a1o = {0.f,0.f,0.f,0.f};
  float l0 = 0.f, l1 = 0.f;

#define ITER(ke, ko, ve, vo)                                                \
  do {                                                                      \
    float4v zero = {0.f,0.f,0.f,0.f};                                       \
    __builtin_amdgcn_s_setprio(1);                                          \
    float4v s0e = __builtin_amdgcn_mfma_f32_16x16x16bf16_1k(ke, qf0, zero, 0,0,0); \
    float4v s0o = __builtin_amdgcn_mfma_f32_16x16x16bf16_1k(ko, qf0, zero, 0,0,0); \
    float4v s1e = __builtin_amdgcn_mfma_f32_16x16x16bf16_1k(ke, qf1, zero, 0,0,0); \
    float4v s1o = __builtin_amdgcn_mfma_f32_16x16x16bf16_1k(ko, qf1, zero, 0,0,0); \
    float p0e0 = fast_exp2(s0e[0]), p0e1 = fast_exp2(s0e[1]);               \
    float p0e2 = fast_exp2(s0e[2]), p0e3 = fast_exp2(s0e[3]);               \
    float p0o0 = fast_exp2(s0o[0]), p0o1 = fast_exp2(s0o[1]);               \
    float p0o2 = fast_exp2(s0o[2]), p0o3 = fast_exp2(s0o[3]);               \
    float p1e0 = fast_exp2(s1e[0]), p1e1 = fast_exp2(s1e[1]);               \
    float p1e2 = fast_exp2(s1e[2]), p1e3 = fast_exp2(s1e[3]);               \
    float p1o0 = fast_exp2(s1o[0]), p1o1 = fast_exp2(s1o[1]);               \
    float p1o2 = fast_exp2(s1o[2]), p1o3 = fast_exp2(s1o[3]);               \
    l0 += (p0e0 + p0e1) + (p0e2 + p0e3) + (p0o0 + p0o1) + (p0o2 + p0o3);    \
    l1 += (p1e0 + p1e1) + (p1e2 + p1e3) + (p1o0 + p1o1) + (p1o2 + p1o3);    \
    short4v pb0e = pack4_bf16(p0e0, p0e1, p0e2, p0e3);                      \
    short4v pb0o = pack4_bf16(p0o0, p0o1, p0o2, p0o3);                      \
    short4v pb1e = pack4_bf16(p1e0, p1e1, p1e2, p1e3);                      \
    short4v pb1o = pack4_bf16(p1o0, p1o1, p1o2, p1o3);                      \
    a0e = __builtin_amdgcn_mfma_f32_16x16x16bf16_1k(ve, pb0e, a0e, 0,0,0);  \
    a0o = __builtin_amdgcn_mfma_f32_16x16x16bf16_1k(vo, pb0o, a0o, 0,0,0);  \
    a1e = __builtin_amdgcn_mfma_f32_16x16x16bf16_1k(ve, pb1e, a1e, 0,0,0);  \
    a1o = __builtin_amdgcn_mfma_f32_16x16x16bf16_1k(vo, pb1o, a1o, 0,0,0);  \
    __builtin_amdgcn_s_setprio(0);                                          \
  } while (0)

  // prologue: fragments for iters 0 (A) and 1 (B)
  short4v kAe = *(const short4v*)(kp);
  short4v kAo = *(const short4v*)(kp + 256);
  short4v vAe = *(const short4v*)(vp);
  short4v vAo = *(const short4v*)(vp + 256);
  short4v kBe = *(const short4v*)(kp + 512);
  short4v kBo = *(const short4v*)(kp + 768);
  short4v vBe = *(const short4v*)(vp + 512);
  short4v vBo = *(const short4v*)(vp + 768);

  #pragma unroll 4
  for (int it2 = 0; it2 < PITERS/2; ++it2) {
    // prefetch iters 2*it2+2 (A') and 2*it2+3 (B'); benign ws over-read at tail
    int oA = (2*it2 + 2) * 512;
    int oB = (2*it2 + 3) * 512;
    short4v nkAe = *(const short4v*)(kp + oA);
    short4v nkAo = *(const short4v*)(kp + oA + 256);
    short4v nvAe = *(const short4v*)(vp + oA);
    short4v nvAo = *(const short4v*)(vp + oA + 256);
    short4v nkBe = *(const short4v*)(kp + oB);
    short4v nkBo = *(const short4v*)(kp + oB + 256);
    short4v nvBe = *(const short4v*)(vp + oB);
    short4v nvBo = *(const short4v*)(vp + oB + 256);

    ITER(kAe, kAo, vAe, vAo);
    ITER(kBe, kBo, vBe, vBo);

    kAe = nkAe; kAo = nkAo; vAe = nvAe; vAo = nvAo;
    kBe = nkBe; kBo = nkBo; vBe = nvBe; vBo = nvBo;
  }
#undef ITER

  // per-wave partial outputs (key-quarter partials)
  float o0[4], o1[4];
  #pragma unroll
  for (int r = 0; r < 4; ++r) {
    o0[r] = a0e[r] + a0o[r];
    o1[r] = a1e[r] + a1o[r];
  }

  // combine the 4 quarters: waves 1..3 publish, wave 0 reduces + stores
  if (quart != 0) {
    float* cp = &comb[quart-1][lane][0];
    cp[0] = o0[0]; cp[1] = o0[1]; cp[2] = o0[2]; cp[3] = o0[3];
    cp[4] = o1[0]; cp[5] = o1[1]; cp[6] = o1[2]; cp[7] = o1[3];
    cp[8] = l0;    cp[9] = l1;
  }
  __syncthreads();
  if (quart == 0) {
    #pragma unroll
    for (int wv = 0; wv < 3; ++wv) {
      const float* cp = &comb[wv][lane][0];
      o0[0] += cp[0]; o0[1] += cp[1]; o0[2] += cp[2]; o0[3] += cp[3];
      o1[0] += cp[4]; o1[1] += cp[5]; o1[2] += cp[6]; o1[3] += cp[7];
      l0 += cp[8];    l1 += cp[9];
    }
    // total l per q (lanes l^16, l^32 hold the same q)
    l0 += __shfl_xor(l0, 16); l0 += __shfl_xor(l0, 32);
    l1 += __shfl_xor(l1, 16); l1 += __shfl_xor(l1, 32);
    float inv0 = 1.0f / l0, inv1 = 1.0f / l1;

    int b = bh >> 2, h = bh & 3;
    float* ob = out + ((size_t)(b*64 + h*16 + g4)) * NTOK;
    #pragma unroll
    for (int r = 0; r < 4; ++r) {
      ob[(size_t)r*NTOK + qbase      + lr] = o0[r] * inv0;
      ob[(size_t)r*NTOK + qbase + 16 + lr] = o1[r] * inv1;
    }
  }
}

extern "C" void kernel_launch(void* const* d_in, const int* in_sizes, int n_in,
                              void* d_out, int out_size, void* d_ws, size_t ws_size,
                              hipStream_t stream) {
  const float* x    = (const float*)d_in[0];   // (2,64,64,64)
  const float* w    = (const float*)d_in[1];   // (192,64)
  const float* bias = (const float*)d_in[2];   // (192,)
  float* out  = (float*)d_out;                 // (2,64,64,64)
  ushort* wsu = (ushort*)d_ws;                 // 3 MB used (+2KB over-read pad)

  qkv_proj <<<512,  192, 0, stream>>>(x, w, bias, wsu);
  attn_mfma<<<1024, 256, 0, stream>>>(wsu, out);
}